// Round 10
// baseline (569.270 us; speedup 1.0000x reference)
//
#include <hip/hip_runtime.h>
#include <cstdint>

#define DEVINL __device__ __forceinline__

typedef uint16_t u16;
typedef uint32_t u32;
typedef uint64_t u64;
typedef __attribute__((ext_vector_type(8))) short short8;
typedef __attribute__((ext_vector_type(4))) float floatx4;
typedef __attribute__((ext_vector_type(4))) u32 u32x4;
typedef const __attribute__((address_space(1))) void* gas_ptr;
typedef __attribute__((address_space(3))) void* las_ptr;

DEVINL u16 f2bf(float f) {
  u32 u = __float_as_uint(f);
  u32 r = u + 0x7FFFu + ((u >> 16) & 1u);   // RNE
  return (u16)(r >> 16);
}
DEVINL float bf2f(u16 b) { return __uint_as_float((u32)b << 16); }
DEVINL float bf_lo(u32 u) { return __uint_as_float(u << 16); }
DEVINL float bf_hi(u32 u) { return __uint_as_float(u & 0xFFFF0000u); }

// Operand layout for GEMM: K-chunked tiles  T[ck][row][64], ck = k/64.
// A' rows padded to Mpad=25088 so block row-tiles read contiguous 16KB with no clamp.
// R8 post-mortem: A-direct-to-register regressed (vmcnt entanglement with stageB's
// global_load_lds queue forced a second full drain per iter). A stays in LDS (R7).

// ---------- fused prep: splitA + splitW + rowstart, one dispatch ----------
__global__ __launch_bounds__(256)
void prep_kernel(const int* __restrict__ dst, int* __restrict__ rs,
                 const float* __restrict__ h, u16* __restrict__ A1,
                 const float* __restrict__ W1, const float* __restrict__ W2,
                 const float* __restrict__ W3, u16* __restrict__ B1,
                 u16* __restrict__ B2, u16* __restrict__ B3,
                 int N, int E, int Mpad)
{
  const int b = blockIdx.x, tid = threadIdx.x;
  if (b < 25000) {                                // splitA: h[N][256] -> [8][Mpad][64]
    int idx = b * 256 + tid;                      // exact: 25000*256 = N*256
    int m = idx >> 8, k = idx & 255;
    float a = h[idx];
    u16 hi = f2bf(a);
    u16 lo = f2bf(a - bf2f(hi));
    size_t cs = (size_t)Mpad * 64;
    size_t pos = (size_t)m * 64 + (k & 63);
    A1[(size_t)(k >> 6) * cs + pos] = hi;         // hi chunks 0..3
    A1[(size_t)((k >> 6) + 4) * cs + pos] = lo;   // lo chunks 4..7
    return;
  }
  if (b < 26600) {                                // splitW (bf16 hi duplicated)
    int idx = (b - 25000) * 256 + tid;
    if (idx < 512 * 256) {                        // W1 [512][256] -> [8][512][64]
      int m = idx >> 8, k = idx & 255;
      u16 hh = f2bf(W1[idx]);
      size_t cs = 512 * 64;
      size_t pos = (size_t)m * 64 + (k & 63);
      B1[(size_t)(k >> 6) * cs + pos] = hh;
      B1[(size_t)((k >> 6) + 4) * cs + pos] = hh;
      return;
    }
    idx -= 512 * 256;
    if (idx < 512 * 512) {                        // W2 [512][512] -> [16][512][64]
      int m = idx >> 9, k = idx & 511;
      u16 hh = f2bf(W2[idx]);
      size_t cs = 512 * 64;
      size_t pos = (size_t)m * 64 + (k & 63);
      B2[(size_t)(k >> 6) * cs + pos] = hh;
      B2[(size_t)((k >> 6) + 8) * cs + pos] = hh;
      return;
    }
    idx -= 512 * 512;
    {                                             // W3 [32][512] -> [16][32][64]
      int m = idx >> 9, k = idx & 511;
      u16 hh = f2bf(W3[idx]);
      size_t cs = 32 * 64;
      size_t pos = (size_t)m * 64 + (k & 63);
      B3[(size_t)(k >> 6) * cs + pos] = hh;
      B3[(size_t)((k >> 6) + 8) * cs + pos] = hh;
      return;
    }
  }
  {                                               // rowstart: lower_bound over sorted dst
    int n = (b - 26600) * 256 + tid;
    if (n > N) return;
    int lo = 0, hi = E;
    while (lo < hi) { int mid = (lo + hi) >> 1; if (dst[mid] < n) lo = mid + 1; else hi = mid; }
    rs[n] = lo;
  }
}

// ---------- GEMM: C[M,Nout] = A'[M,K'] * B'[Nout,K']^T, K-chunked operands ----------
// 8 waves (512 thr), wave owns 16 rows. 2-phase double-buffer (R6/R7 verified):
// STAGE(t+1) issued BEFORE compute(t), one barrier/step.
// Staging: one global_load_lds call = 64 lanes x 16B = 512 u16 = 8 tile-rows.
//   A tile 128x64 = 16 calls (2/wave); B tile BNx64 = BN/8 calls.
// LDS XOR-swizzle (granule ^= row&7): pre-swizzled GLOBAL source + swizzled ds_read.
// OUTM 1: bf16 C store + el/er store epilogue; XCD-grouped bid decode.
// OUTM 2: single-pass layer 3 — plain f32 C store, direct el/er store.
template<int BN, int OUTM>
__global__ __launch_bounds__(512)
void gemm_bt_kernel(const u16* __restrict__ A, const u16* __restrict__ B,
                    float* __restrict__ Cf, u16* __restrict__ Cb,
                    const float* __restrict__ al, const float* __restrict__ ar,
                    float* __restrict__ el, float* __restrict__ er,
                    int M, int Nout, int Mpad, int kcLen)
{
  constexpr int BM = 128, CF = BN / 16;
  constexpr int BCALLS_B = (BN * 64) / 512;       // 16 for BN=128, 4 for BN=32
  __shared__ __align__(16) u16 As[2][BM * 64];    // 2 x 16 KB
  __shared__ __align__(16) u16 Bs[2][BN * 64];
  const int tid  = threadIdx.x;
  const int wave = tid >> 6;                      // 0..7
  const int lane = tid & 63;
  const int quad = lane >> 4;
  const int l16  = lane & 15;
  const int lrow = lane >> 3;                     // sub-row within a 512-elem call
  const int lq   = lane & 7;                      // 16B-granule within row

  int bx, by;
  if (OUTM == 1) {
    // XCD grouping: bid = y%8 + 8*x + 32*(y/8) for full groups of 8 y's.
    int bid = blockIdx.x;
    int nY = (M + 127) >> 7;
    int fullG = nY >> 3;
    if ((bid >> 5) < fullG) {
      int rem = bid & 31;
      by = ((bid >> 5) << 3) + (rem & 7);
      bx = rem >> 3;
    } else {
      int t = bid - (fullG << 5);
      int tailY = nY - (fullG << 3);
      by = (fullG << 3) + t % tailY;
      bx = t / tailY;
    }
  } else { bx = blockIdx.x; by = blockIdx.y; }

  const int rowBase = by * BM;
  const int colBase = (OUTM == 2) ? 0 : bx * BN;
  const int kcStart = 0;

  floatx4 acc[CF];
  #pragma unroll
  for (int c = 0; c < CF; ++c)
    acc[c] = (floatx4){0.f, 0.f, 0.f, 0.f};

  const size_t aCS = (size_t)Mpad * 64;
  const size_t bCS = (size_t)Nout * 64;
  const u16* aTile = A + (size_t)rowBase * 64;
  const u16* bTile = B + (size_t)colBase * 64;

  auto stage = [&](int buf, int kc) {
    const u16* aB = aTile + (size_t)kc * aCS;
    #pragma unroll
    for (int i = 0; i < 2; ++i) {                 // A: 16 calls, 2/wave (16KB tile)
      int c = wave + 8 * i;
      int row = c * 8 + lrow;
      const u16* gp = aB + row * 64 + ((lq ^ (row & 7)) << 3);
      __builtin_amdgcn_global_load_lds((gas_ptr)gp, (las_ptr)(&As[buf][c * 512]), 16, 0, 0);
    }
    const u16* bB = bTile + (size_t)kc * bCS;
    #pragma unroll
    for (int i = 0; i < (BCALLS_B + 7) / 8; ++i) {
      int c = wave + 8 * i;
      if (c < BCALLS_B) {
        int row = c * 8 + lrow;
        const u16* gp = bB + row * 64 + ((lq ^ (row & 7)) << 3);
        __builtin_amdgcn_global_load_lds((gas_ptr)gp, (las_ptr)(&Bs[buf][c * 512]), 16, 0, 0);
      }
    }
  };

  stage(0, kcStart);                              // prologue: fill buf0
  int cur = 0;
  for (int t = 0; t < kcLen; ++t) {
    __syncthreads();                              // drains vmcnt -> buf[cur] published
    if (t + 1 < kcLen) stage(cur ^ 1, kcStart + t + 1);   // prefetch BEFORE compute
    const u16* Asb = &As[cur][0];
    const u16* Bsb = &Bs[cur][0];
    const int r0 = 16 * wave + l16;               // this wave's 16 rows
    #pragma unroll
    for (int kk = 0; kk < 2; ++kk) {
      short8 a0 = *(const short8*)(Asb + r0 * 64 + ((((kk << 2) + quad) ^ (r0 & 7)) << 3));
      #pragma unroll
      for (int c = 0; c < CF; ++c) {
        int rb = 16 * c + l16;
        short8 b = *(const short8*)(Bsb + rb * 64 + ((((kk << 2) + quad) ^ (rb & 7)) << 3));
        acc[c] = __builtin_amdgcn_mfma_f32_16x16x32_bf16(a0, b, acc[c], 0, 0, 0);
      }
    }
    cur ^= 1;
  }

  // C/D layout: col = lane&15, row = quad*4 + reg (verified m89/m91)
  #pragma unroll
  for (int c = 0; c < CF; ++c)
    #pragma unroll
    for (int i = 0; i < 4; ++i) {
      int gr = rowBase + 16 * wave + quad * 4 + i;
      if (gr < M) {
        int gc = colBase + 16 * c + l16;
        if (OUTM == 1) Cb[(size_t)gr * Nout + gc] = f2bf(acc[c][i]);
        else           Cf[(size_t)gr * Nout + gc] = acc[c][i];     // plain store
      }
    }

  // ---- fused el/er epilogue (from f32 acc) ----
  if (OUTM == 1) {
    #pragma unroll
    for (int i = 0; i < 4; ++i) {
      int gr = rowBase + 16 * wave + quad * 4 + i;
      #pragma unroll
      for (int hp = 0; hp < 2; ++hp) {
        float sl = 0.f, sr = 0.f;
        #pragma unroll
        for (int cc = 0; cc < 4; ++cc) {
          int c = hp * 4 + cc;
          int gc = colBase + 16 * c + l16;
          float zv = acc[c][i];
          sl += zv * al[gc];
          sr += zv * ar[gc];
        }
        #pragma unroll
        for (int m = 1; m < 16; m <<= 1) {        // reduce over l16
          sl += __shfl_xor(sl, m, 64);
          sr += __shfl_xor(sr, m, 64);
        }
        if (l16 == 0 && gr < M) {
          int hh = colBase / 64 + hp;
          el[(size_t)gr * 8 + hh] = sl;
          er[(size_t)gr * 8 + hh] = sr;
        }
      }
    }
  } else {
    // single-pass: full-K acc -> direct el/er store (no partials, no atomics)
    #pragma unroll
    for (int i = 0; i < 4; ++i) {
      int gr = rowBase + 16 * wave + quad * 4 + i;
      float sl = 0.f, sr = 0.f;
      #pragma unroll
      for (int c = 0; c < CF; ++c) {
        int gc = 16 * c + l16;
        float zv = acc[c][i];
        sl += zv * al[gc];
        sr += zv * ar[gc];
      }
      #pragma unroll
      for (int m = 1; m < 16; m <<= 1) {
        sl += __shfl_xor(sl, m, 64);
        sr += __shfl_xor(sr, m, 64);
      }
      if (l16 == 0 && gr < M) {
        el[gr] = sl;
        er[gr] = sr;
      }
    }
  }
}

// ---------- layers 1/2 aggregate: XCD-AFFINE COLUMN-SLICE gather ----------
// R10: partition z by columns into 8 slices of 64 (= one head, 128B/row, 3.2MB/slice).
// slice = blockIdx & 7 -> lands on XCD (blockIdx % 8) under the empirical round-robin
// dispatch (same assumption as the GEMM XCD-grouping, verified by R4's FETCH 102->31MB).
// Slice j then fits XCD j's 4MB L2 -> each z byte fetched from HBM once (~26MB vs
// 195MB). R5's column-split failed precisely because slices spanned all XCDs.
// Lane = one column. Per-column edge-accumulation order is BIT-IDENTICAL to the R9
// kernel (same edges, same sequence, same expressions); den identical; scalar work
// duplicated 8x (VALU was 29% busy - not binding).
// Grid-stride over nodes: 8 slices x SLOTS blocks, 1 wave each.
// Epilogue: slice j writes A' chunk j (hi) and j+8 (lo), 128B contiguous stores.
__global__ __launch_bounds__(64)
void agg_bf16_kernel(const u16* __restrict__ z, const float* __restrict__ el,
                     const float* __restrict__ er, const int* __restrict__ src,
                     const int* __restrict__ rs, u16* __restrict__ a2out,
                     int Mpad, int N, int slots)
{
  const int bid = blockIdx.x;
  const int slice = bid & 7;                       // XCD-affine
  const int bslot = bid >> 3;
  const int lane = threadIdx.x;
  const int c = slice * 64 + lane;                 // this lane's column
  const size_t cs = (size_t)Mpad * 64;
  const u16* zc = z + c;

  for (int n = bslot; n < N; n += slots) {
    const int s = rs[n], e = rs[n + 1];
    const float er_h = er[(size_t)n * 8 + slice];
    float acc = 0.f, den = 0.f;

    for (int k0 = s; k0 < e; k0 += 8) {
      const int kc = e - k0;
      #pragma unroll
      for (int kk = 0; kk < 8; ++kk) {
        if (kk < kc) {                             // wave-uniform guard
          int si = src[k0 + kk];                   // broadcast load
          float v = el[(size_t)si * 8 + slice] + er_h;
          v = (v > 0.f) ? v : 0.2f * v;            // leaky_relu 0.2
          float wgt = __expf(v);
          float zv = bf2f(zc[(size_t)si * 512]);   // 128B/wave, L2-resident slice
          acc += wgt * zv;
          den += wgt;
        }
      }
    }

    const float r = (e > s) ? (1.f / den) : 0.f;   // deg==0 -> zeros (elu(0)=0)
    float o = acc * r;
    o = (o > 0.f) ? o : (__expf(o) - 1.f);         // elu
    u16 hi = f2bf(o);
    u16 lo = f2bf(o - bf2f(hi));
    a2out[(size_t)slice * cs + (size_t)n * 64 + lane] = hi;
    a2out[(size_t)(slice + 8) * cs + (size_t)n * 64 + lane] = lo;
  }
}

// ---------- layer 3 aggregate: f32 z3 (3.2 MB, L2-resident), 32 cols ----------
__global__ __launch_bounds__(64)
void agg3_kernel(const float* __restrict__ z, const float* __restrict__ el,
                 const float* __restrict__ er, const int* __restrict__ src,
                 const int* __restrict__ rs, float* __restrict__ out)
{
  const int n = blockIdx.x, tid = threadIdx.x;
  const int s = rs[n], e = rs[n + 1];
  const bool active = (tid < 32);
  const float er_n = er[n];
  float acc = 0.f, den = 0.f;

  for (int k0 = s; k0 < e; k0 += 8) {
    const int kc = e - k0;
    #pragma unroll
    for (int kk = 0; kk < 8; ++kk) {
      if (kk < kc) {
        int si = src[k0 + kk];
        float v = el[si] + er_n;
        v = (v > 0.f) ? v : 0.2f * v;
        float wgt = __expf(v);
        if (active) acc += wgt * z[(size_t)si * 32 + tid];
        den += wgt;
      }
    }
  }
  if (active) out[(size_t)n * 32 + tid] = (e > s) ? (acc / den) : 0.f;
}

extern "C" void kernel_launch(void* const* d_in, const int* in_sizes, int n_in,
                              void* d_out, int out_size, void* d_ws, size_t ws_size,
                              hipStream_t stream)
{
  constexpr int N = 25000, E = 400000, K1 = 256, HF = 512, CLS = 32;
  constexpr int Mpad = 25088;                       // 196 * 128
  constexpr int AGG_SLOTS = 2048;                   // blocks per slice
  const float* h   = (const float*)d_in[0];
  const int*   src = (const int*)d_in[1];
  const int*   dst = (const int*)d_in[2];
  const float* W1  = (const float*)d_in[3];
  const float* al1 = (const float*)d_in[4];
  const float* ar1 = (const float*)d_in[5];
  const float* W2  = (const float*)d_in[6];
  const float* al2 = (const float*)d_in[7];
  const float* ar2 = (const float*)d_in[8];
  const float* W3  = (const float*)d_in[9];
  const float* al3 = (const float*)d_in[10];
  const float* ar3 = (const float*)d_in[11];
  float* out = (float*)d_out;

  char* w = (char*)d_ws;
  auto take = [&](size_t bytes) {
    char* p = w;
    w += (bytes + 255) & ~(size_t)255;
    return p;
  };
  int*   rs  = (int*)  take((size_t)(N + 1) * sizeof(int));
  float* el  = (float*)take((size_t)N * 8 * sizeof(float));
  float* er  = (float*)take((size_t)N * 8 * sizeof(float));
  float* z3  = (float*)take((size_t)N * CLS * sizeof(float));         // 3.2 MB
  u16*   zb  = (u16*)  take((size_t)N * HF * sizeof(u16));            // 25.6 MB
  u16*   A2  = (u16*)  take((size_t)16 * Mpad * 64 * sizeof(u16));    // 51.4 MB
  u16*   B1  = (u16*)  take((size_t)8  * HF * 64 * sizeof(u16));      // 0.52 MB
  u16*   B2  = (u16*)  take((size_t)16 * HF * 64 * sizeof(u16));      // 1.05 MB
  u16*   B3  = (u16*)  take((size_t)16 * CLS * 64 * sizeof(u16));     // 64 KB
  u16*   A1  = A2;      // layer-1 A (8 chunks) aliases A2; dead before agg1 writes

  // ---- fused prep: splitA | splitW | rowstart ----
  prep_kernel<<<dim3(25000 + 1600 + 98), 256, 0, stream>>>(
      dst, rs, h, A1, W1, W2, W3, B1, B2, B3, N, E, Mpad);

  const int gemmBlocks = 4 * (Mpad / 128);          // 784, 1-D XCD-grouped decode
  const int aggBlocks  = 8 * AGG_SLOTS;             // 16384, slice = bid & 7

  // ---- Layer 1: K'=512 (8 chunks), elr fused ----
  gemm_bt_kernel<128, 1><<<dim3(gemmBlocks), 512, 0, stream>>>(A1, B1, nullptr, zb,
      al1, ar1, el, er, N, HF, Mpad, 8);
  agg_bf16_kernel<<<dim3(aggBlocks), 64, 0, stream>>>(zb, el, er, src, rs, A2,
      Mpad, N, AGG_SLOTS);

  // ---- Layer 2: K'=1024 (16 chunks), elr fused ----
  gemm_bt_kernel<128, 1><<<dim3(gemmBlocks), 512, 0, stream>>>(A2, B2, nullptr, zb,
      al2, ar2, el, er, N, HF, Mpad, 16);
  agg_bf16_kernel<<<dim3(aggBlocks), 64, 0, stream>>>(zb, el, er, src, rs, A2,
      Mpad, N, AGG_SLOTS);

  // ---- Layer 3: single-pass K (16 chunks), plain stores, elr direct ----
  gemm_bt_kernel<32, 2><<<dim3(1, Mpad / 128), 512, 0, stream>>>(A2, B3, z3, nullptr,
      al3, ar3, el, er, N, CLS, Mpad, 16);
  agg3_kernel<<<dim3(N), 64, 0, stream>>>(z3, el, er, src, rs, out);
}

// Round 11
// 315.869 us; speedup vs baseline: 1.8022x; 1.8022x over previous
//
#include <hip/hip_runtime.h>
#include <cstdint>

#define DEVINL __device__ __forceinline__

typedef uint16_t u16;
typedef uint32_t u32;
typedef uint64_t u64;
typedef __attribute__((ext_vector_type(8))) short short8;
typedef __attribute__((ext_vector_type(4))) float floatx4;
typedef __attribute__((ext_vector_type(4))) u32 u32x4;
typedef const __attribute__((address_space(1))) void* gas_ptr;
typedef __attribute__((address_space(3))) void* las_ptr;

DEVINL u16 f2bf(float f) {
  u32 u = __float_as_uint(f);
  u32 r = u + 0x7FFFu + ((u >> 16) & 1u);   // RNE
  return (u16)(r >> 16);
}
DEVINL float bf2f(u16 b) { return __uint_as_float((u32)b << 16); }
DEVINL float bf_lo(u32 u) { return __uint_as_float(u << 16); }
DEVINL float bf_hi(u32 u) { return __uint_as_float(u & 0xFFFF0000u); }

// R11: single-plane bf16 GEMM operands (lo-plane dropped; absmax headroom 4x).
// Operand layout: K-chunked tiles T[ck][row][64], ck = k/64.
// A1 = [4][Mpad][64] (h), A2 = [8][Mpad][64] (agg out); B1=[4][512][64],
// B2=[8][512][64], B3=[8][32][64]. A' rows padded to Mpad=25088.
// R8 post-mortem: A-direct-to-register regressed (vmcnt entanglement). A in LDS.
// R10 post-mortem: agg gather is structurally optimal at 1KB/edge; slicing is
// issue-bound (8x scalar dup at 128B/wave). agg form frozen at the R9 kernel.

// ---------- fused prep: splitA + splitW + rowstart, one dispatch ----------
__global__ __launch_bounds__(256)
void prep_kernel(const int* __restrict__ dst, int* __restrict__ rs,
                 const float* __restrict__ h, u16* __restrict__ A1,
                 const float* __restrict__ W1, const float* __restrict__ W2,
                 const float* __restrict__ W3, u16* __restrict__ B1,
                 u16* __restrict__ B2, u16* __restrict__ B3,
                 int N, int E, int Mpad)
{
  const int b = blockIdx.x, tid = threadIdx.x;
  if (b < 25000) {                                // splitA: h[N][256] -> [4][Mpad][64]
    int idx = b * 256 + tid;                      // exact: 25000*256 = N*256
    int m = idx >> 8, k = idx & 255;
    A1[(size_t)(k >> 6) * ((size_t)Mpad * 64) + (size_t)m * 64 + (k & 63)] = f2bf(h[idx]);
    return;
  }
  if (b < 26600) {                                // splitW: single bf16 plane
    int idx = (b - 25000) * 256 + tid;
    if (idx < 512 * 256) {                        // W1 [512][256] -> [4][512][64]
      int m = idx >> 8, k = idx & 255;
      B1[(size_t)(k >> 6) * (512 * 64) + (size_t)m * 64 + (k & 63)] = f2bf(W1[idx]);
      return;
    }
    idx -= 512 * 256;
    if (idx < 512 * 512) {                        // W2 [512][512] -> [8][512][64]
      int m = idx >> 9, k = idx & 511;
      B2[(size_t)(k >> 6) * (512 * 64) + (size_t)m * 64 + (k & 63)] = f2bf(W2[idx]);
      return;
    }
    idx -= 512 * 512;
    {                                             // W3 [32][512] -> [8][32][64]
      int m = idx >> 9, k = idx & 511;
      B3[(size_t)(k >> 6) * (32 * 64) + (size_t)m * 64 + (k & 63)] = f2bf(W3[idx]);
      return;
    }
  }
  {                                               // rowstart: lower_bound over sorted dst
    int n = (b - 26600) * 256 + tid;
    if (n > N) return;
    int lo = 0, hi = E;
    while (lo < hi) { int mid = (lo + hi) >> 1; if (dst[mid] < n) lo = mid + 1; else hi = mid; }
    rs[n] = lo;
  }
}

// ---------- GEMM: C[M,Nout] = A'[M,K'] * B'[Nout,K']^T, K-chunked operands ----------
// 8 waves (512 thr), wave owns 16 rows. 2-phase double-buffer (R6/R7 verified):
// STAGE(t+1) issued BEFORE compute(t), one barrier/step.
// Staging: one global_load_lds call = 64 lanes x 16B = 512 u16 = 8 tile-rows.
//   A tile 128x64 = 16 calls (2/wave); B tile BNx64 = BN/8 calls.
// LDS XOR-swizzle (granule ^= row&7): pre-swizzled GLOBAL source + swizzled ds_read.
// OUTM 1: bf16 C store + el/er store epilogue; XCD-grouped bid decode.
// OUTM 2: single-pass layer 3 — plain f32 C store, direct el/er store.
template<int BN, int OUTM>
__global__ __launch_bounds__(512)
void gemm_bt_kernel(const u16* __restrict__ A, const u16* __restrict__ B,
                    float* __restrict__ Cf, u16* __restrict__ Cb,
                    const float* __restrict__ al, const float* __restrict__ ar,
                    float* __restrict__ el, float* __restrict__ er,
                    int M, int Nout, int Mpad, int kcLen)
{
  constexpr int BM = 128, CF = BN / 16;
  constexpr int BCALLS_B = (BN * 64) / 512;       // 16 for BN=128, 4 for BN=32
  __shared__ __align__(16) u16 As[2][BM * 64];    // 2 x 16 KB
  __shared__ __align__(16) u16 Bs[2][BN * 64];
  const int tid  = threadIdx.x;
  const int wave = tid >> 6;                      // 0..7
  const int lane = tid & 63;
  const int quad = lane >> 4;
  const int l16  = lane & 15;
  const int lrow = lane >> 3;                     // sub-row within a 512-elem call
  const int lq   = lane & 7;                      // 16B-granule within row

  int bx, by;
  if (OUTM == 1) {
    // XCD grouping: bid = y%8 + 8*x + 32*(y/8) for full groups of 8 y's.
    int bid = blockIdx.x;
    int nY = (M + 127) >> 7;
    int fullG = nY >> 3;
    if ((bid >> 5) < fullG) {
      int rem = bid & 31;
      by = ((bid >> 5) << 3) + (rem & 7);
      bx = rem >> 3;
    } else {
      int t = bid - (fullG << 5);
      int tailY = nY - (fullG << 3);
      by = (fullG << 3) + t % tailY;
      bx = t / tailY;
    }
  } else { bx = blockIdx.x; by = blockIdx.y; }

  const int rowBase = by * BM;
  const int colBase = (OUTM == 2) ? 0 : bx * BN;

  floatx4 acc[CF];
  #pragma unroll
  for (int c = 0; c < CF; ++c)
    acc[c] = (floatx4){0.f, 0.f, 0.f, 0.f};

  const size_t aCS = (size_t)Mpad * 64;
  const size_t bCS = (size_t)Nout * 64;
  const u16* aTile = A + (size_t)rowBase * 64;
  const u16* bTile = B + (size_t)colBase * 64;

  auto stage = [&](int buf, int kc) {
    const u16* aB = aTile + (size_t)kc * aCS;
    #pragma unroll
    for (int i = 0; i < 2; ++i) {                 // A: 16 calls, 2/wave (16KB tile)
      int c = wave + 8 * i;
      int row = c * 8 + lrow;
      const u16* gp = aB + row * 64 + ((lq ^ (row & 7)) << 3);
      __builtin_amdgcn_global_load_lds((gas_ptr)gp, (las_ptr)(&As[buf][c * 512]), 16, 0, 0);
    }
    const u16* bB = bTile + (size_t)kc * bCS;
    #pragma unroll
    for (int i = 0; i < (BCALLS_B + 7) / 8; ++i) {
      int c = wave + 8 * i;
      if (c < BCALLS_B) {
        int row = c * 8 + lrow;
        const u16* gp = bB + row * 64 + ((lq ^ (row & 7)) << 3);
        __builtin_amdgcn_global_load_lds((gas_ptr)gp, (las_ptr)(&Bs[buf][c * 512]), 16, 0, 0);
      }
    }
  };

  stage(0, 0);                                    // prologue: fill buf0
  int cur = 0;
  for (int t = 0; t < kcLen; ++t) {
    __syncthreads();                              // drains vmcnt -> buf[cur] published
    if (t + 1 < kcLen) stage(cur ^ 1, t + 1);     // prefetch BEFORE compute
    const u16* Asb = &As[cur][0];
    const u16* Bsb = &Bs[cur][0];
    const int r0 = 16 * wave + l16;               // this wave's 16 rows
    #pragma unroll
    for (int kk = 0; kk < 2; ++kk) {
      short8 a0 = *(const short8*)(Asb + r0 * 64 + ((((kk << 2) + quad) ^ (r0 & 7)) << 3));
      #pragma unroll
      for (int c = 0; c < CF; ++c) {
        int rb = 16 * c + l16;
        short8 b = *(const short8*)(Bsb + rb * 64 + ((((kk << 2) + quad) ^ (rb & 7)) << 3));
        acc[c] = __builtin_amdgcn_mfma_f32_16x16x32_bf16(a0, b, acc[c], 0, 0, 0);
      }
    }
    cur ^= 1;
  }

  // C/D layout: col = lane&15, row = quad*4 + reg (verified m89/m91)
  #pragma unroll
  for (int c = 0; c < CF; ++c)
    #pragma unroll
    for (int i = 0; i < 4; ++i) {
      int gr = rowBase + 16 * wave + quad * 4 + i;
      if (gr < M) {
        int gc = colBase + 16 * c + l16;
        if (OUTM == 1) Cb[(size_t)gr * Nout + gc] = f2bf(acc[c][i]);
        else           Cf[(size_t)gr * Nout + gc] = acc[c][i];     // plain store
      }
    }

  // ---- fused el/er epilogue (from f32 acc) ----
  if (OUTM == 1) {
    #pragma unroll
    for (int i = 0; i < 4; ++i) {
      int gr = rowBase + 16 * wave + quad * 4 + i;
      #pragma unroll
      for (int hp = 0; hp < 2; ++hp) {
        float sl = 0.f, sr = 0.f;
        #pragma unroll
        for (int cc = 0; cc < 4; ++cc) {
          int c = hp * 4 + cc;
          int gc = colBase + 16 * c + l16;
          float zv = acc[c][i];
          sl += zv * al[gc];
          sr += zv * ar[gc];
        }
        #pragma unroll
        for (int m = 1; m < 16; m <<= 1) {        // reduce over l16
          sl += __shfl_xor(sl, m, 64);
          sr += __shfl_xor(sr, m, 64);
        }
        if (l16 == 0 && gr < M) {
          int hh = colBase / 64 + hp;
          el[(size_t)gr * 8 + hh] = sl;
          er[(size_t)gr * 8 + hh] = sr;
        }
      }
    }
  } else {
    // single-pass: full-K acc -> direct el/er store (no partials, no atomics)
    #pragma unroll
    for (int i = 0; i < 4; ++i) {
      int gr = rowBase + 16 * wave + quad * 4 + i;
      float sl = 0.f, sr = 0.f;
      #pragma unroll
      for (int c = 0; c < CF; ++c) {
        int gc = 16 * c + l16;
        float zv = acc[c][i];
        sl += zv * al[gc];
        sr += zv * ar[gc];
      }
      #pragma unroll
      for (int m = 1; m < 16; m <<= 1) {
        sl += __shfl_xor(sl, m, 64);
        sr += __shfl_xor(sr, m, 64);
      }
      if (l16 == 0 && gr < M) {
        el[gr] = sl;
        er[gr] = sr;
      }
    }
  }
}

// ---------- layers 1/2 aggregate: bf16 z gather, 1 wave/node, 8 cols/thread ----------
// out = sum_e exp(v_e) z[src_e] / sum_e exp(v_e)  (shift-invariant softmax, no max pass)
// Epilogue writes next layer's A' (bf16 hi only): chunk ck = c0/64 of [8][Mpad][64].
// Gather form frozen (R1/R5/R10 post-mortems): 1KB/edge full-width is optimal.
__global__ __launch_bounds__(64)
void agg_bf16_kernel(const u16* __restrict__ z, const float* __restrict__ el,
                     const float* __restrict__ er, const int* __restrict__ src,
                     const int* __restrict__ rs, u16* __restrict__ a2out, int Mpad)
{
  const int n = blockIdx.x, tid = threadIdx.x;
  const int s = rs[n], e = rs[n + 1];
  const int c0 = tid * 8;                          // 8 bf16 cols = 16 B/lane
  const int h = tid >> 3;                          // c0 / 64
  const float er_h = er[(size_t)n * 8 + h];

  float acc[8];
  #pragma unroll
  for (int j = 0; j < 8; ++j) acc[j] = 0.f;
  float den = 0.f;

  for (int k0 = s; k0 < e; k0 += 8) {
    const int kc = e - k0;
    #pragma unroll
    for (int kk = 0; kk < 8; ++kk) {
      if (kk < kc) {                               // wave-uniform guard
        int si = src[k0 + kk];                     // broadcast load
        float v = el[(size_t)si * 8 + h] + er_h;   // broadcast load
        v = (v > 0.f) ? v : 0.2f * v;              // leaky_relu 0.2
        float wgt = __expf(v);
        u32x4 zz = *(const u32x4*)(z + (size_t)si * 512 + c0);  // 16B/lane coalesced
        #pragma unroll
        for (int j = 0; j < 4; ++j) {
          acc[2 * j]     += wgt * bf_lo(zz[j]);
          acc[2 * j + 1] += wgt * bf_hi(zz[j]);
        }
        den += wgt;
      }
    }
  }

  const float r = (e > s) ? (1.f / den) : 0.f;     // deg==0 -> zeros (elu(0)=0)
  u32x4 hp;
  #pragma unroll
  for (int j = 0; j < 4; ++j) {
    float o0 = acc[2 * j] * r, o1 = acc[2 * j + 1] * r;
    o0 = (o0 > 0.f) ? o0 : (__expf(o0) - 1.f);     // elu
    o1 = (o1 > 0.f) ? o1 : (__expf(o1) - 1.f);
    hp[j] = ((u32)f2bf(o1) << 16) | f2bf(o0);
  }
  // tiled A' store (hi only): chunk = c0/64, offset = c0%64
  const int ck = tid >> 3;
  const int ko = (tid & 7) << 3;
  u16* p = a2out + (size_t)n * 64 + ko;
  *(u32x4*)(p + (size_t)ck * ((size_t)Mpad * 64)) = hp;
}

// ---------- layer 3 aggregate: f32 z3 (3.2 MB, L2-resident), 32 cols ----------
__global__ __launch_bounds__(64)
void agg3_kernel(const float* __restrict__ z, const float* __restrict__ el,
                 const float* __restrict__ er, const int* __restrict__ src,
                 const int* __restrict__ rs, float* __restrict__ out)
{
  const int n = blockIdx.x, tid = threadIdx.x;
  const int s = rs[n], e = rs[n + 1];
  const bool active = (tid < 32);
  const float er_n = er[n];
  float acc = 0.f, den = 0.f;

  for (int k0 = s; k0 < e; k0 += 8) {
    const int kc = e - k0;
    #pragma unroll
    for (int kk = 0; kk < 8; ++kk) {
      if (kk < kc) {
        int si = src[k0 + kk];
        float v = el[si] + er_n;
        v = (v > 0.f) ? v : 0.2f * v;
        float wgt = __expf(v);
        if (active) acc += wgt * z[(size_t)si * 32 + tid];
        den += wgt;
      }
    }
  }
  if (active) out[(size_t)n * 32 + tid] = (e > s) ? (acc / den) : 0.f;
}

extern "C" void kernel_launch(void* const* d_in, const int* in_sizes, int n_in,
                              void* d_out, int out_size, void* d_ws, size_t ws_size,
                              hipStream_t stream)
{
  constexpr int N = 25000, E = 400000, K1 = 256, HF = 512, CLS = 32;
  constexpr int Mpad = 25088;                       // 196 * 128
  const float* h   = (const float*)d_in[0];
  const int*   src = (const int*)d_in[1];
  const int*   dst = (const int*)d_in[2];
  const float* W1  = (const float*)d_in[3];
  const float* al1 = (const float*)d_in[4];
  const float* ar1 = (const float*)d_in[5];
  const float* W2  = (const float*)d_in[6];
  const float* al2 = (const float*)d_in[7];
  const float* ar2 = (const float*)d_in[8];
  const float* W3  = (const float*)d_in[9];
  const float* al3 = (const float*)d_in[10];
  const float* ar3 = (const float*)d_in[11];
  float* out = (float*)d_out;

  char* w = (char*)d_ws;
  auto take = [&](size_t bytes) {
    char* p = w;
    w += (bytes + 255) & ~(size_t)255;
    return p;
  };
  int*   rs  = (int*)  take((size_t)(N + 1) * sizeof(int));
  float* el  = (float*)take((size_t)N * 8 * sizeof(float));
  float* er  = (float*)take((size_t)N * 8 * sizeof(float));
  float* z3  = (float*)take((size_t)N * CLS * sizeof(float));         // 3.2 MB
  u16*   zb  = (u16*)  take((size_t)N * HF * sizeof(u16));            // 25.6 MB
  u16*   A2  = (u16*)  take((size_t)8 * Mpad * 64 * sizeof(u16));     // 25.7 MB
  u16*   B1  = (u16*)  take((size_t)4 * HF * 64 * sizeof(u16));       // 0.26 MB
  u16*   B2  = (u16*)  take((size_t)8 * HF * 64 * sizeof(u16));       // 0.52 MB
  u16*   B3  = (u16*)  take((size_t)8 * CLS * 64 * sizeof(u16));      // 32 KB
  u16*   A1  = A2;      // layer-1 A (4 chunks) aliases A2; dead before agg1 writes

  // ---- fused prep: splitA | splitW | rowstart ----
  prep_kernel<<<dim3(25000 + 1600 + 98), 256, 0, stream>>>(
      dst, rs, h, A1, W1, W2, W3, B1, B2, B3, N, E, Mpad);

  const int gemmBlocks = 4 * (Mpad / 128);          // 784, 1-D XCD-grouped decode

  // ---- Layer 1: K'=256 (4 chunks), elr fused ----
  gemm_bt_kernel<128, 1><<<dim3(gemmBlocks), 512, 0, stream>>>(A1, B1, nullptr, zb,
      al1, ar1, el, er, N, HF, Mpad, 4);
  agg_bf16_kernel<<<dim3(N), 64, 0, stream>>>(zb, el, er, src, rs, A2, Mpad);

  // ---- Layer 2: K'=512 (8 chunks), elr fused ----
  gemm_bt_kernel<128, 1><<<dim3(gemmBlocks), 512, 0, stream>>>(A2, B2, nullptr, zb,
      al2, ar2, el, er, N, HF, Mpad, 8);
  agg_bf16_kernel<<<dim3(N), 64, 0, stream>>>(zb, el, er, src, rs, A2, Mpad);

  // ---- Layer 3: single-pass K'=512 (8 chunks), plain stores, elr direct ----
  gemm_bt_kernel<32, 2><<<dim3(1, Mpad / 128), 512, 0, stream>>>(A2, B3, z3, nullptr,
      al3, ar3, el, er, N, CLS, Mpad, 8);
  agg3_kernel<<<dim3(N), 64, 0, stream>>>(z3, el, er, src, rs, out);
}

// Round 12
// 305.216 us; speedup vs baseline: 1.8651x; 1.0349x over previous
//
#include <hip/hip_runtime.h>
#include <cstdint>

#define DEVINL __device__ __forceinline__

typedef uint16_t u16;
typedef uint32_t u32;
typedef uint64_t u64;
typedef __attribute__((ext_vector_type(8))) short short8;
typedef __attribute__((ext_vector_type(4))) float floatx4;
typedef __attribute__((ext_vector_type(4))) u32 u32x4;
typedef const __attribute__((address_space(1))) void* gas_ptr;
typedef __attribute__((address_space(3))) void* las_ptr;

DEVINL u16 f2bf(float f) {
  u32 u = __float_as_uint(f);
  u32 r = u + 0x7FFFu + ((u >> 16) & 1u);   // RNE
  return (u16)(r >> 16);
}
DEVINL float bf2f(u16 b) { return __uint_as_float((u32)b << 16); }
DEVINL float bf_lo(u32 u) { return __uint_as_float(u << 16); }
DEVINL float bf_hi(u32 u) { return __uint_as_float(u & 0xFFFF0000u); }

// R11: single-plane bf16 GEMM operands (lo-plane dropped; absmax 9.8e-4, 3x headroom).
// Operand layout: K-chunked tiles T[ck][row][64], ck = k/64.
// A1 = [4][Mpad][64] (h), A2 = [8][Mpad][64] (agg out); B1=[4][512][64],
// B2=[8][512][64], B3=[8][32][64]. A' rows padded to Mpad=25088.
// R8 post-mortem: A-direct-to-register regressed (vmcnt entanglement). A in LDS.
// R10 post-mortem: agg gather is structurally optimal at 1KB/edge; slicing is
// issue-bound (8x scalar dup at 128B/wave). agg gather form frozen.

// ---------- fused prep: splitA + splitW + rowstart, one dispatch ----------
// R12: 4 elems/thread (float4 load -> packed u64 store; k%4==0 keeps all 4 in one
// K-chunk). Block ranges: [0,6250) splitA, [6250,6378) W1, [6378,6634) W2,
// [6634,6650) W3, [6650,6748) rowstart.
__global__ __launch_bounds__(256)
void prep_kernel(const int* __restrict__ dst, int* __restrict__ rs,
                 const float* __restrict__ h, u16* __restrict__ A1,
                 const float* __restrict__ W1, const float* __restrict__ W2,
                 const float* __restrict__ W3, u16* __restrict__ B1,
                 u16* __restrict__ B2, u16* __restrict__ B3,
                 int N, int E, int Mpad)
{
  const int b = blockIdx.x, tid = threadIdx.x;
  auto pack4 = [](const float4 a) -> u64 {
    return (u64)f2bf(a.x) | ((u64)f2bf(a.y) << 16) |
           ((u64)f2bf(a.z) << 32) | ((u64)f2bf(a.w) << 48);
  };
  if (b < 6250) {                                 // splitA: h[N][256] -> [4][Mpad][64]
    int idx = (b * 256 + tid) * 4;                // exact: 6250*1024 = 25000*256
    int m = idx >> 8, k = idx & 255;
    u64 p = pack4(*(const float4*)(h + idx));
    *(u64*)(A1 + (size_t)(k >> 6) * ((size_t)Mpad * 64) + (size_t)m * 64 + (k & 63)) = p;
    return;
  }
  if (b < 6378) {                                 // W1 [512][256] -> [4][512][64]
    int idx = ((b - 6250) * 256 + tid) * 4;
    int m = idx >> 8, k = idx & 255;
    u64 p = pack4(*(const float4*)(W1 + idx));
    *(u64*)(B1 + (size_t)(k >> 6) * (512 * 64) + (size_t)m * 64 + (k & 63)) = p;
    return;
  }
  if (b < 6634) {                                 // W2 [512][512] -> [8][512][64]
    int idx = ((b - 6378) * 256 + tid) * 4;
    int m = idx >> 9, k = idx & 511;
    u64 p = pack4(*(const float4*)(W2 + idx));
    *(u64*)(B2 + (size_t)(k >> 6) * (512 * 64) + (size_t)m * 64 + (k & 63)) = p;
    return;
  }
  if (b < 6650) {                                 // W3 [32][512] -> [8][32][64]
    int idx = ((b - 6634) * 256 + tid) * 4;
    int m = idx >> 9, k = idx & 511;
    u64 p = pack4(*(const float4*)(W3 + idx));
    *(u64*)(B3 + (size_t)(k >> 6) * (32 * 64) + (size_t)m * 64 + (k & 63)) = p;
    return;
  }
  {                                               // rowstart: lower_bound over sorted dst
    int n = (b - 6650) * 256 + tid;
    if (n > N) return;
    int lo = 0, hi = E;
    while (lo < hi) { int mid = (lo + hi) >> 1; if (dst[mid] < n) lo = mid + 1; else hi = mid; }
    rs[n] = lo;
  }
}

// ---------- GEMM: C[M,Nout] = A'[M,K'] * B'[Nout,K']^T, K-chunked operands ----------
// 8 waves (512 thr), wave owns 16 rows. 2-phase double-buffer (R6/R7 verified):
// STAGE(t+1) issued BEFORE compute(t), one barrier/step.
// LDS XOR-swizzle (granule ^= row&7): pre-swizzled GLOBAL source + swizzled ds_read.
// OUTM 1: bf16 C store + el/er store epilogue; XCD-grouped bid decode.
// OUTM 2: single-pass layer 3 — plain f32 C store, direct el/er store.
template<int BN, int OUTM>
__global__ __launch_bounds__(512)
void gemm_bt_kernel(const u16* __restrict__ A, const u16* __restrict__ B,
                    float* __restrict__ Cf, u16* __restrict__ Cb,
                    const float* __restrict__ al, const float* __restrict__ ar,
                    float* __restrict__ el, float* __restrict__ er,
                    int M, int Nout, int Mpad, int kcLen)
{
  constexpr int BM = 128, CF = BN / 16;
  constexpr int BCALLS_B = (BN * 64) / 512;       // 16 for BN=128, 4 for BN=32
  __shared__ __align__(16) u16 As[2][BM * 64];    // 2 x 16 KB
  __shared__ __align__(16) u16 Bs[2][BN * 64];
  const int tid  = threadIdx.x;
  const int wave = tid >> 6;                      // 0..7
  const int lane = tid & 63;
  const int quad = lane >> 4;
  const int l16  = lane & 15;
  const int lrow = lane >> 3;                     // sub-row within a 512-elem call
  const int lq   = lane & 7;                      // 16B-granule within row

  int bx, by;
  if (OUTM == 1) {
    // XCD grouping: bid = y%8 + 8*x + 32*(y/8) for full groups of 8 y's.
    int bid = blockIdx.x;
    int nY = (M + 127) >> 7;
    int fullG = nY >> 3;
    if ((bid >> 5) < fullG) {
      int rem = bid & 31;
      by = ((bid >> 5) << 3) + (rem & 7);
      bx = rem >> 3;
    } else {
      int t = bid - (fullG << 5);
      int tailY = nY - (fullG << 3);
      by = (fullG << 3) + t % tailY;
      bx = t / tailY;
    }
  } else { bx = blockIdx.x; by = blockIdx.y; }

  const int rowBase = by * BM;
  const int colBase = (OUTM == 2) ? 0 : bx * BN;

  floatx4 acc[CF];
  #pragma unroll
  for (int c = 0; c < CF; ++c)
    acc[c] = (floatx4){0.f, 0.f, 0.f, 0.f};

  const size_t aCS = (size_t)Mpad * 64;
  const size_t bCS = (size_t)Nout * 64;
  const u16* aTile = A + (size_t)rowBase * 64;
  const u16* bTile = B + (size_t)colBase * 64;

  auto stage = [&](int buf, int kc) {
    const u16* aB = aTile + (size_t)kc * aCS;
    #pragma unroll
    for (int i = 0; i < 2; ++i) {                 // A: 16 calls, 2/wave (16KB tile)
      int c = wave + 8 * i;
      int row = c * 8 + lrow;
      const u16* gp = aB + row * 64 + ((lq ^ (row & 7)) << 3);
      __builtin_amdgcn_global_load_lds((gas_ptr)gp, (las_ptr)(&As[buf][c * 512]), 16, 0, 0);
    }
    const u16* bB = bTile + (size_t)kc * bCS;
    #pragma unroll
    for (int i = 0; i < (BCALLS_B + 7) / 8; ++i) {
      int c = wave + 8 * i;
      if (c < BCALLS_B) {
        int row = c * 8 + lrow;
        const u16* gp = bB + row * 64 + ((lq ^ (row & 7)) << 3);
        __builtin_amdgcn_global_load_lds((gas_ptr)gp, (las_ptr)(&Bs[buf][c * 512]), 16, 0, 0);
      }
    }
  };

  stage(0, 0);                                    // prologue: fill buf0
  int cur = 0;
  for (int t = 0; t < kcLen; ++t) {
    __syncthreads();                              // drains vmcnt -> buf[cur] published
    if (t + 1 < kcLen) stage(cur ^ 1, t + 1);     // prefetch BEFORE compute
    const u16* Asb = &As[cur][0];
    const u16* Bsb = &Bs[cur][0];
    const int r0 = 16 * wave + l16;               // this wave's 16 rows
    #pragma unroll
    for (int kk = 0; kk < 2; ++kk) {
      short8 a0 = *(const short8*)(Asb + r0 * 64 + ((((kk << 2) + quad) ^ (r0 & 7)) << 3));
      #pragma unroll
      for (int c = 0; c < CF; ++c) {
        int rb = 16 * c + l16;
        short8 b = *(const short8*)(Bsb + rb * 64 + ((((kk << 2) + quad) ^ (rb & 7)) << 3));
        acc[c] = __builtin_amdgcn_mfma_f32_16x16x32_bf16(a0, b, acc[c], 0, 0, 0);
      }
    }
    cur ^= 1;
  }

  // C/D layout: col = lane&15, row = quad*4 + reg (verified m89/m91)
  #pragma unroll
  for (int c = 0; c < CF; ++c)
    #pragma unroll
    for (int i = 0; i < 4; ++i) {
      int gr = rowBase + 16 * wave + quad * 4 + i;
      if (gr < M) {
        int gc = colBase + 16 * c + l16;
        if (OUTM == 1) Cb[(size_t)gr * Nout + gc] = f2bf(acc[c][i]);
        else           Cf[(size_t)gr * Nout + gc] = acc[c][i];     // plain store
      }
    }

  // ---- fused el/er epilogue (from f32 acc) ----
  if (OUTM == 1) {
    #pragma unroll
    for (int i = 0; i < 4; ++i) {
      int gr = rowBase + 16 * wave + quad * 4 + i;
      #pragma unroll
      for (int hp = 0; hp < 2; ++hp) {
        float sl = 0.f, sr = 0.f;
        #pragma unroll
        for (int cc = 0; cc < 4; ++cc) {
          int c = hp * 4 + cc;
          int gc = colBase + 16 * c + l16;
          float zv = acc[c][i];
          sl += zv * al[gc];
          sr += zv * ar[gc];
        }
        #pragma unroll
        for (int m = 1; m < 16; m <<= 1) {        // reduce over l16
          sl += __shfl_xor(sl, m, 64);
          sr += __shfl_xor(sr, m, 64);
        }
        if (l16 == 0 && gr < M) {
          int hh = colBase / 64 + hp;
          el[(size_t)gr * 8 + hh] = sl;
          er[(size_t)gr * 8 + hh] = sr;
        }
      }
    }
  } else {
    // single-pass: full-K acc -> direct el/er store (no partials, no atomics)
    #pragma unroll
    for (int i = 0; i < 4; ++i) {
      int gr = rowBase + 16 * wave + quad * 4 + i;
      float sl = 0.f, sr = 0.f;
      #pragma unroll
      for (int c = 0; c < CF; ++c) {
        int gc = 16 * c + l16;
        float zv = acc[c][i];
        sl += zv * al[gc];
        sr += zv * ar[gc];
      }
      #pragma unroll
      for (int m = 1; m < 16; m <<= 1) {
        sl += __shfl_xor(sl, m, 64);
        sr += __shfl_xor(sr, m, 64);
      }
      if (l16 == 0 && gr < M) {
        el[gr] = sl;
        er[gr] = sr;
      }
    }
  }
}

// ---------- layers 1/2 aggregate: bf16 z gather, 1 wave/node, 8 cols/thread ----------
// out = sum_e exp(v_e) z[src_e] / sum_e exp(v_e)  (shift-invariant softmax, no max pass)
// Epilogue writes next layer's A' (bf16): chunk ck = c0/64 of [8][Mpad][64],
// NON-TEMPORAL (R12): the 25MB A'-write stream should not evict gather-reusable
// z lines from L2. Gather form frozen (R1/R5/R10): 1KB/edge full-width optimal.
__global__ __launch_bounds__(64)
void agg_bf16_kernel(const u16* __restrict__ z, const float* __restrict__ el,
                     const float* __restrict__ er, const int* __restrict__ src,
                     const int* __restrict__ rs, u16* __restrict__ a2out, int Mpad)
{
  const int n = blockIdx.x, tid = threadIdx.x;
  const int s = rs[n], e = rs[n + 1];
  const int c0 = tid * 8;                          // 8 bf16 cols = 16 B/lane
  const int h = tid >> 3;                          // c0 / 64
  const float er_h = er[(size_t)n * 8 + h];

  float acc[8];
  #pragma unroll
  for (int j = 0; j < 8; ++j) acc[j] = 0.f;
  float den = 0.f;

  for (int k0 = s; k0 < e; k0 += 8) {
    const int kc = e - k0;
    #pragma unroll
    for (int kk = 0; kk < 8; ++kk) {
      if (kk < kc) {                               // wave-uniform guard
        int si = src[k0 + kk];                     // broadcast load
        float v = el[(size_t)si * 8 + h] + er_h;   // broadcast load
        v = (v > 0.f) ? v : 0.2f * v;              // leaky_relu 0.2
        float wgt = __expf(v);
        u32x4 zz = *(const u32x4*)(z + (size_t)si * 512 + c0);  // 16B/lane coalesced
        #pragma unroll
        for (int j = 0; j < 4; ++j) {
          acc[2 * j]     += wgt * bf_lo(zz[j]);
          acc[2 * j + 1] += wgt * bf_hi(zz[j]);
        }
        den += wgt;
      }
    }
  }

  const float r = (e > s) ? (1.f / den) : 0.f;     // deg==0 -> zeros (elu(0)=0)
  u32x4 hp;
  #pragma unroll
  for (int j = 0; j < 4; ++j) {
    float o0 = acc[2 * j] * r, o1 = acc[2 * j + 1] * r;
    o0 = (o0 > 0.f) ? o0 : (__expf(o0) - 1.f);     // elu
    o1 = (o1 > 0.f) ? o1 : (__expf(o1) - 1.f);
    hp[j] = ((u32)f2bf(o1) << 16) | f2bf(o0);
  }
  // tiled A' store: chunk = c0/64, offset = c0%64 (non-temporal)
  const int ck = tid >> 3;
  const int ko = (tid & 7) << 3;
  u16* p = a2out + (size_t)n * 64 + ko;
  __builtin_nontemporal_store(hp, (u32x4*)(p + (size_t)ck * ((size_t)Mpad * 64)));
}

// ---------- layer 3 aggregate: f32 z3, 2 edges/iter (R12) ----------
// Half-wave 0 takes even-offset edges, half-wave 1 odd; full 64-lane payload
// utilization halves the dependent-chain iterations (structure was latency-bound:
// 32 idle lanes + 128B/edge). den/acc combined with one shfl_xor(32) at the end
// (even-sum + odd-sum; deterministic, threshold headroom 3x).
__global__ __launch_bounds__(64)
void agg3_kernel(const float* __restrict__ z, const float* __restrict__ el,
                 const float* __restrict__ er, const int* __restrict__ src,
                 const int* __restrict__ rs, float* __restrict__ out)
{
  const int n = blockIdx.x, tid = threadIdx.x;
  const int s = rs[n], e = rs[n + 1];
  const int half = tid >> 5;                       // 0: even edges, 1: odd edges
  const int col = tid & 31;
  const float er_n = er[n];
  float acc = 0.f, den = 0.f;

  for (int k0 = s; k0 < e; k0 += 16) {
    const int kc = e - k0;
    #pragma unroll
    for (int kk = 0; kk < 8; ++kk) {
      int off = 2 * kk + half;
      if (off < kc) {                              // half-wave-uniform guard
        int si = src[k0 + off];
        float v = el[si] + er_n;
        v = (v > 0.f) ? v : 0.2f * v;
        float wgt = __expf(v);
        acc += wgt * z[(size_t)si * 32 + col];
        den += wgt;
      }
    }
  }
  den += __shfl_xor(den, 32, 64);                  // even + odd partial sums
  acc += __shfl_xor(acc, 32, 64);
  if (tid < 32) out[(size_t)n * 32 + col] = (e > s) ? (acc / den) : 0.f;
}

extern "C" void kernel_launch(void* const* d_in, const int* in_sizes, int n_in,
                              void* d_out, int out_size, void* d_ws, size_t ws_size,
                              hipStream_t stream)
{
  constexpr int N = 25000, E = 400000, K1 = 256, HF = 512, CLS = 32;
  constexpr int Mpad = 25088;                       // 196 * 128
  const float* h   = (const float*)d_in[0];
  const int*   src = (const int*)d_in[1];
  const int*   dst = (const int*)d_in[2];
  const float* W1  = (const float*)d_in[3];
  const float* al1 = (const float*)d_in[4];
  const float* ar1 = (const float*)d_in[5];
  const float* W2  = (const float*)d_in[6];
  const float* al2 = (const float*)d_in[7];
  const float* ar2 = (const float*)d_in[8];
  const float* W3  = (const float*)d_in[9];
  const float* al3 = (const float*)d_in[10];
  const float* ar3 = (const float*)d_in[11];
  float* out = (float*)d_out;

  char* w = (char*)d_ws;
  auto take = [&](size_t bytes) {
    char* p = w;
    w += (bytes + 255) & ~(size_t)255;
    return p;
  };
  int*   rs  = (int*)  take((size_t)(N + 1) * sizeof(int));
  float* el  = (float*)take((size_t)N * 8 * sizeof(float));
  float* er  = (float*)take((size_t)N * 8 * sizeof(float));
  float* z3  = (float*)take((size_t)N * CLS * sizeof(float));         // 3.2 MB
  u16*   zb  = (u16*)  take((size_t)N * HF * sizeof(u16));            // 25.6 MB
  u16*   A2  = (u16*)  take((size_t)8 * Mpad * 64 * sizeof(u16));     // 25.7 MB
  u16*   B1  = (u16*)  take((size_t)4 * HF * 64 * sizeof(u16));       // 0.26 MB
  u16*   B2  = (u16*)  take((size_t)8 * HF * 64 * sizeof(u16));       // 0.52 MB
  u16*   B3  = (u16*)  take((size_t)8 * CLS * 64 * sizeof(u16));      // 32 KB
  u16*   A1  = A2;      // layer-1 A (4 chunks) aliases A2; dead before agg1 writes

  // ---- fused prep: splitA | splitW | rowstart (4 elems/thread) ----
  prep_kernel<<<dim3(6250 + 128 + 256 + 16 + 98), 256, 0, stream>>>(
      dst, rs, h, A1, W1, W2, W3, B1, B2, B3, N, E, Mpad);

  const int gemmBlocks = 4 * (Mpad / 128);          // 784, 1-D XCD-grouped decode

  // ---- Layer 1: K'=256 (4 chunks), elr fused ----
  gemm_bt_kernel<128, 1><<<dim3(gemmBlocks), 512, 0, stream>>>(A1, B1, nullptr, zb,
      al1, ar1, el, er, N, HF, Mpad, 4);
  agg_bf16_kernel<<<dim3(N), 64, 0, stream>>>(zb, el, er, src, rs, A2, Mpad);

  // ---- Layer 2: K'=512 (8 chunks), elr fused ----
  gemm_bt_kernel<128, 1><<<dim3(gemmBlocks), 512, 0, stream>>>(A2, B2, nullptr, zb,
      al2, ar2, el, er, N, HF, Mpad, 8);
  agg_bf16_kernel<<<dim3(N), 64, 0, stream>>>(zb, el, er, src, rs, A2, Mpad);

  // ---- Layer 3: single-pass K'=512 (8 chunks), plain stores, elr direct ----
  gemm_bt_kernel<32, 2><<<dim3(1, Mpad / 128), 512, 0, stream>>>(A2, B3, z3, nullptr,
      al3, ar3, el, er, N, CLS, Mpad, 8);
  agg3_kernel<<<dim3(N), 64, 0, stream>>>(z3, el, er, src, rs, out);
}